// Round 6
// baseline (1371.780 us; speedup 1.0000x reference)
//
#include <hip/hip_runtime.h>
#include <hip/hip_bf16.h>
#include <cstdint>

// InterModalityUpdate — f32 in/out, bf16 MFMA internally (fp32 accum).
// R7: attn K/V LDS-staged via global_load_lds (411us -> ~250us each).
// R8/R9: GEMM 256x256/BK=32 3-buffer counted-vmcnt (352 -> 264us, MfmaUtil 35%,
//     conflicts 0). Coarse {all-reads -> all-MFMA} shape left LDS pipe and MFMA
//     pipe serialized (m196's isolated result).
// R10: full 8-phase template port (m201 structure): BK=64, 8 x 16KB half-tile
//     slots (A_K0/A_K1/B_K0/B_K1 x 2 parity), per phase {4-8 ds_read; stage 1
//     half-tile; bar; 16 MFMA (setprio); bar}; B-frags register-reused across
//     row-half phases so one slot frees per phase; each stage targets the slot
//     freed one phase earlier (WAR via phase barrier). vmcnt(6) at phases 4/8
//     only (certifies all but newest 3 half-tiles; ledger verified: 14->6 at
//     every checkpoint); vmcnt(0) at last iteration's p4. Numerics identical.
// Dims fixed: B=16 N=M=512 VS=2048 QS=1024 OS=2048 H=16 DH=128.

typedef __hip_bfloat16 bf16;
typedef __attribute__((ext_vector_type(8))) __bf16 bf16x8;
typedef __attribute__((ext_vector_type(4))) float f32x4;
typedef __attribute__((ext_vector_type(4))) unsigned short us4;
typedef __attribute__((ext_vector_type(8))) unsigned short us8;

#define AS1 __attribute__((address_space(1)))
#define AS3 __attribute__((address_space(3)))

__device__ __forceinline__ void gl_lds16(const bf16* g, bf16* l) {
    __builtin_amdgcn_global_load_lds((AS1 void*)(uintptr_t)(g), (AS3 void*)(l), 16, 0, 0);
}

__device__ __forceinline__ bf16x8 ld8(const bf16* p) { return *(const bf16x8*)p; }

__device__ __forceinline__ f32x4 mfma16(bf16x8 a, bf16x8 b, f32x4 c) {
    return __builtin_amdgcn_mfma_f32_16x16x32_bf16(a, b, c, 0, 0, 0);
}

// f32 -> bf16 bits, round-to-nearest-even (finite inputs)
__device__ __forceinline__ unsigned short f2bs(float f) {
    unsigned u = __builtin_bit_cast(unsigned, f);
    unsigned r = u + 0x7FFFu + ((u >> 16) & 1u);
    return (unsigned short)(r >> 16);
}

// ---------------------------------------------------------------------------
// f32 -> bf16 convert into left columns of a wider bf16 matrix. 8 elems/thread.
__global__ __launch_bounds__(256) void cvt_cols_k(
    const float* __restrict__ src, bf16* __restrict__ dst,
    int cprShift, int dstStride, int totalChunks)
{
    const int id = blockIdx.x * 256 + threadIdx.x;
    if (id >= totalChunks) return;
    const int row = id >> cprShift;
    const int cc = (id - (row << cprShift)) << 3;
    const float* s = src + ((size_t)row << (cprShift + 3)) + cc;
    const float4 a = *(const float4*)s;
    const float4 b = *(const float4*)(s + 4);
    us8 o;
    o[0] = f2bs(a.x); o[1] = f2bs(a.y); o[2] = f2bs(a.z); o[3] = f2bs(a.w);
    o[4] = f2bs(b.x); o[5] = f2bs(b.y); o[6] = f2bs(b.z); o[7] = f2bs(b.w);
    *(us8*)(dst + (size_t)row * dstStride + cc) = o;
}

// ---------------------------------------------------------------------------
// Fused convert+transpose for weights. f32 R x C -> bf16 C x R.
__global__ __launch_bounds__(256) void cvt_transpose_k(
    const float* __restrict__ in, unsigned short* __restrict__ out,
    int inStride, int outStride)
{
    __shared__ unsigned short tile[64][65];
    const int ti = blockIdx.x * 64;
    const int tj = blockIdx.y * 64;
    const int t = threadIdx.x;
    const int r = t >> 4;
    const int c4 = (t & 15) << 2;
#pragma unroll
    for (int i = 0; i < 4; ++i) {
        const float4 v = *(const float4*)(in + (size_t)(tj + r + i * 16) * inStride + ti + c4);
        tile[r + i * 16][c4 + 0] = f2bs(v.x);
        tile[r + i * 16][c4 + 1] = f2bs(v.y);
        tile[r + i * 16][c4 + 2] = f2bs(v.z);
        tile[r + i * 16][c4 + 3] = f2bs(v.w);
    }
    __syncthreads();
#pragma unroll
    for (int i = 0; i < 4; ++i) {
        const int orow = ti + r + i * 16;
        us4 v;
        v[0] = tile[c4 + 0][r + i * 16];
        v[1] = tile[c4 + 1][r + i * 16];
        v[2] = tile[c4 + 2][r + i * 16];
        v[3] = tile[c4 + 3][r + i * 16];
        *(us4*)(out + (size_t)orow * outStride + tj + c4) = v;
    }
}

// ---------------------------------------------------------------------------
// bf16 tiled transpose (per-head value slices). grid.z slice offset:
// (z>>4)*inOffB + (z&15)*inOffH.
__global__ __launch_bounds__(256) void transpose_k(
    const unsigned short* __restrict__ in, unsigned short* __restrict__ out,
    int inStride, int outStride, size_t inOffB, int inOffH, size_t outSliceStride)
{
    __shared__ unsigned short tile[64][65];
    const int z = blockIdx.z;
    const unsigned short* inp = in + (size_t)(z >> 4) * inOffB + (size_t)(z & 15) * inOffH;
    unsigned short* outp = out + (size_t)z * outSliceStride;
    const int ti = blockIdx.x * 64;
    const int tj = blockIdx.y * 64;
    const int t = threadIdx.x;
    const int r = t >> 4;
    const int c4 = (t & 15) << 2;
#pragma unroll
    for (int i = 0; i < 4; ++i) {
        us4 v = *(const us4*)(inp + (size_t)(tj + r + i * 16) * inStride + ti + c4);
        tile[r + i * 16][c4 + 0] = v[0];
        tile[r + i * 16][c4 + 1] = v[1];
        tile[r + i * 16][c4 + 2] = v[2];
        tile[r + i * 16][c4 + 3] = v[3];
    }
    __syncthreads();
#pragma unroll
    for (int i = 0; i < 4; ++i) {
        const int orow = ti + r + i * 16;
        us4 v;
        v[0] = tile[c4 + 0][r + i * 16];
        v[1] = tile[c4 + 1][r + i * 16];
        v[2] = tile[c4 + 2][r + i * 16];
        v[3] = tile[c4 + 3][r + i * 16];
        *(us4*)(outp + (size_t)orow * outStride + tj + c4) = v;
    }
}

// ---------------------------------------------------------------------------
// C = relu(A @ B + bias) [* mask[row]]; BT[n][k]. 256x256 tile, BK=64,
// 8 waves (2M x 4N), wave tile 128x64. 8-phase schedule (see header).
// LDS: 8 half-tile slots x 16KB; slot = parity*4 + {A_K0=0,A_K1=1,B_K0=2,B_K1=3}.
// Within-slot layout [256 rows][4 chunks of 8 bf16], stored chunk j holds
// global chunk j ^ ((row>>1)&3); read chunk = quad ^ ((l16>>1)&3) (0-conflict,
// verified R8). K must be a multiple of 128 (NT even).
template <typename OutT>
__global__ __launch_bounds__(512, 2) void gemm_bt(
    const bf16* __restrict__ A, const bf16* __restrict__ BT,
    const float* __restrict__ bias, const float* __restrict__ mask,
    OutT* __restrict__ C, int K, int lda, int ldb, int ldc)
{
    __shared__ __align__(16) bf16 smem[65536];   // 8 x 8192 bf16 = 128 KB
    const int tid = threadIdx.x;
    const int lane = tid & 63;
    const int l16 = lane & 15;
    const int quad = lane >> 4;
    const int wave = tid >> 6;
    const int wm = wave >> 2;            // 0..1  (row half)
    const int wn = wave & 3;             // 0..3  (col quarter)
    const int rofs = ((quad ^ ((l16 >> 1) & 3)) << 3);  // swizzled read chunk
    const size_t row0 = (size_t)blockIdx.y * 256;
    const size_t col0 = (size_t)blockIdx.x * 256;

    // staging: 1024 chunks/slot; thread owns chunks tid (row r0) and tid+512
    // (row r0+128, same stored chunk & same global-chunk xor => same jg).
    const int r0 = tid >> 2;
    const int jg0 = (((tid & 3) ^ ((r0 >> 1) & 3)) << 3);
    const bf16* pA = A + (row0 + r0) * lda + jg0;
    const bf16* pB = BT + (col0 + r0) * ldb + jg0;
    const size_t lda128 = (size_t)128 * lda;
    const size_t ldb128 = (size_t)128 * ldb;

    const f32x4 z4 = {0.f, 0.f, 0.f, 0.f};
    f32x4 acc[8][4];
#pragma unroll
    for (int r = 0; r < 8; ++r)
#pragma unroll
        for (int c = 0; c < 4; ++c) acc[r][c] = z4;

    const int NT = K >> 6;     // 64-wide K tiles
    const int NI = NT >> 1;    // iterations (2 tiles each)

#define STG_A(SL, TT, KH) do { \
    gl_lds16(pA + (TT) * 64 + (KH) * 32, smem + (SL) * 8192 + tid * 8); \
    gl_lds16(pA + lda128 + (TT) * 64 + (KH) * 32, smem + (SL) * 8192 + 4096 + tid * 8); \
} while (0)
#define STG_B(SL, TT, KH) do { \
    gl_lds16(pB + (TT) * 64 + (KH) * 32, smem + (SL) * 8192 + tid * 8); \
    gl_lds16(pB + ldb128 + (TT) * 64 + (KH) * 32, smem + (SL) * 8192 + 4096 + tid * 8); \
} while (0)
#define LDA4(SL, RH) \
    _Pragma("unroll") \
    for (int j = 0; j < 4; ++j) \
        af[j] = ld8(smem + (SL) * 8192 + (wm * 128 + (RH) * 64 + j * 16 + l16) * 32 + rofs);
#define LDB4(SL) \
    _Pragma("unroll") \
    for (int j = 0; j < 4; ++j) \
        bfr[j] = ld8(smem + (SL) * 8192 + (wn * 64 + j * 16 + l16) * 32 + rofs);
#define MM16(RH) \
    __builtin_amdgcn_s_setprio(1); \
    _Pragma("unroll") \
    for (int j = 0; j < 4; ++j) \
        _Pragma("unroll") \
        for (int c = 0; c < 4; ++c) \
            acc[(RH) * 4 + j][c] = mfma16(af[j], bfr[c], acc[(RH) * 4 + j][c]); \
    __builtin_amdgcn_s_setprio(0);
#define BARR() do { asm volatile("" ::: "memory"); __builtin_amdgcn_s_barrier(); asm volatile("" ::: "memory"); } while (0)

    // prologue: tile0 (slots 2,0,3,1) + tile1's B_K0,A_K0,B_K1 (slots 6,4,7).
    // vmcnt(6) leaves the newest 3 half-tiles in flight, certifies tile0.
    STG_B(2, 0, 0); STG_A(0, 0, 0); STG_B(3, 0, 1); STG_A(1, 0, 1);
    STG_B(6, 1, 0); STG_A(4, 1, 0); STG_B(7, 1, 1);
    asm volatile("s_waitcnt vmcnt(6)" ::: "memory");
    BARR();

    bf16x8 af[4], bfr[4];

    for (int i = 0; i < NI; ++i) {
        const int U = 2 * i;
        const bool st = (U + 2) < NT;   // (U+3<NT) == st since U,NT even
        // ---- p1: tile U, K0, rows-half0; stage A_K1(U+1) -> slot 5
        LDB4(2); LDA4(0, 0);
        STG_A(5, U + 1, 1);
        BARR();
        MM16(0);
        BARR();
        // ---- p2: tile U, K0, rows-half1 (B reused); stage B_K0(U+2) -> slot 2
        LDA4(0, 1);
        if (st) STG_B(2, U + 2, 0);
        BARR();
        MM16(1);
        BARR();
        // ---- p3: tile U, K1, rows-half0; stage A_K0(U+2) -> slot 0
        LDB4(3); LDA4(1, 0);
        if (st) STG_A(0, U + 2, 0);
        BARR();
        MM16(0);
        BARR();
        // ---- p4: tile U, K1, rows-half1; stage B_K1(U+2) -> slot 3; vmcnt
        LDA4(1, 1);
        if (st) STG_B(3, U + 2, 1);
        BARR();
        MM16(1);
        if (st) asm volatile("s_waitcnt vmcnt(6)" ::: "memory");
        else    asm volatile("s_waitcnt vmcnt(0)" ::: "memory");
        BARR();
        // ---- p5: tile U+1, K0, rows-half0; stage A_K1(U+2) -> slot 1
        LDB4(6); LDA4(4, 0);
        if (st) STG_A(1, U + 2, 1);
        BARR();
        MM16(0);
        BARR();
        // ---- p6: tile U+1, K0, rows-half1; stage B_K0(U+3) -> slot 6
        LDA4(4, 1);
        if (st) STG_B(6, U + 3, 0);
        BARR();
        MM16(1);
        BARR();
        // ---- p7: tile U+1, K1, rows-half0; stage A_K0(U+3) -> slot 4
        LDB4(7); LDA4(5, 0);
        if (st) STG_A(4, U + 3, 0);
        BARR();
        MM16(0);
        BARR();
        // ---- p8: tile U+1, K1, rows-half1; stage B_K1(U+3) -> slot 7; vmcnt
        LDA4(5, 1);
        if (st) STG_B(7, U + 3, 1);
        BARR();
        MM16(1);
        if (st) asm volatile("s_waitcnt vmcnt(6)" ::: "memory");
        BARR();
    }
#undef STG_A
#undef STG_B
#undef LDA4
#undef LDB4
#undef MM16
#undef BARR

    asm volatile("" ::: "memory");
    __syncthreads();   // all waves done with K-loop before smem reuse

    float bcol[4];
#pragma unroll
    for (int fc = 0; fc < 4; ++fc) bcol[fc] = bias[col0 + wn * 64 + fc * 16 + l16];

    if constexpr (sizeof(OutT) == 2) {
        unsigned short* stg = (unsigned short*)smem;   // [32][264]
#pragma unroll
        for (int p = 0; p < 8; ++p) {
            if (wm == (p >> 2)) {
#pragma unroll
                for (int d = 0; d < 2; ++d) {
                    const int fr = (p & 3) * 2 + d;
#pragma unroll
                    for (int fc = 0; fc < 4; ++fc) {
                        const int lcol = wn * 64 + fc * 16 + l16;
#pragma unroll
                        for (int g = 0; g < 4; ++g) {
                            const int lrow = d * 16 + quad * 4 + g;
                            const size_t grow = row0 + (size_t)p * 32 + lrow;
                            float v = acc[fr][fc][g] + bcol[fc];
                            v = v > 0.f ? v : 0.f;
                            if (mask) v *= mask[grow];
                            stg[lrow * 264 + lcol] = f2bs(v);
                        }
                    }
                }
            }
            asm volatile("" ::: "memory");
            __syncthreads();
            const int srow = tid >> 4;            // 0..31
            const int scol = (tid & 15) * 16;     // 0..240
            const us8 o0 = *(const us8*)(stg + srow * 264 + scol);
            const us8 o1 = *(const us8*)(stg + srow * 264 + scol + 8);
            OutT* dst = C + (row0 + p * 32 + srow) * ldc + col0 + scol;
            *(us8*)dst = o0;
            *(us8*)(dst + 8) = o1;
            __syncthreads();
        }
    } else {
        float* stg = (float*)smem;   // [32][260]
#pragma unroll
        for (int p = 0; p < 8; ++p) {
            if (wm == (p >> 2)) {
#pragma unroll
                for (int d = 0; d < 2; ++d) {
                    const int fr = (p & 3) * 2 + d;
#pragma unroll
                    for (int fc = 0; fc < 4; ++fc) {
                        const int lcol = wn * 64 + fc * 16 + l16;
#pragma unroll
                        for (int g = 0; g < 4; ++g) {
                            const int lrow = d * 16 + quad * 4 + g;
                            const size_t grow = row0 + (size_t)p * 32 + lrow;
                            float v = acc[fr][fc][g] + bcol[fc];
                            v = v > 0.f ? v : 0.f;
                            if (mask) v *= mask[grow];
                            stg[lrow * 260 + lcol] = v;
                        }
                    }
                }
            }
            asm volatile("" ::: "memory");
            __syncthreads();
            const int srow = tid >> 4;            // 0..31
            const int scol = (tid & 15) * 16;     // 0..240
            float* dst = (float*)C + (row0 + p * 32 + srow) * ldc + col0 + scol;
            const float* s = stg + srow * 260 + scol;
            *(f32x4*)(dst + 0)  = *(const f32x4*)(s + 0);
            *(f32x4*)(dst + 4)  = *(const f32x4*)(s + 4);
            *(f32x4*)(dst + 8)  = *(const f32x4*)(s + 8);
            *(f32x4*)(dst + 12) = *(const f32x4*)(s + 12);
            __syncthreads();
        }
    }
}

// ---------------------------------------------------------------------------
// Cross attention. grid.x = Lq/32, grid.y = B*H. 128 thr = 2 waves x 16 q-rows.
// K/V staged through 16KB LDS tile via global_load_lds (zero VGPR, async),
// XOR-swizzled source+read (rule #21; linear LDS dest). Unchanged from R8.
__global__ __launch_bounds__(128) void attn_k(
    const bf16* __restrict__ Q, const bf16* __restrict__ Kk,
    const bf16* __restrict__ VT, const float* __restrict__ kmask,
    bf16* __restrict__ Out,
    int Lq, int Lk, int qStride, int kStride, int outStride, int outColOff)
{
    const int bh = blockIdx.y;
    const int b = bh >> 4, h = bh & 15;
    const int n0 = blockIdx.x * 32;
    const int tid = threadIdx.x;
    const int wave = tid >> 6, lane = tid & 63;
    const int l16 = lane & 15, quad = lane >> 4;

    __shared__ __align__(16) bf16 smem[16640 + 8192]; // A: Qs/Ps; B: KV tile
    bf16* kv = smem + 16640;

    // stage Q tile (32 rows x 128 d) into region A
#pragma unroll
    for (int i = 0; i < 4; ++i) {
        const int e = i * 1024 + tid * 8;
        const int r = e >> 7, d = e & 127;
        gl_lds16(Q + (size_t)(b * Lq + n0 + r) * qStride + h * 128 + d, smem + e);
    }
    __syncthreads();

    bf16x8 aq[4];
#pragma unroll
    for (int ks = 0; ks < 4; ++ks)
        aq[ks] = ld8(smem + (wave * 16 + l16) * 128 + ks * 32 + quad * 8);
    __syncthreads();   // union: both waves done reading Qs before Ps overwrites

    // ---- QK^T: 8 rounds of 64 K-rows staged in region B -------------------
    const bf16* Kb = Kk + (size_t)b * Lk * kStride + h * 128;
    f32x4 S[32];
    const int swz = (l16 & 7);
#pragma unroll
    for (int kt = 0; kt < 8; ++kt) {
#pragma unroll
        for (int c = 0; c < 8; ++c) {
            const int e = c * 1024 + tid * 8;
            const int r = e >> 7;
            const int j = (e >> 3) & 15;
            gl_lds16(Kb + (size_t)(kt * 64 + r) * kStride + ((j ^ (r & 7)) << 3), kv + e);
        }
        __syncthreads();
        __builtin_amdgcn_s_setprio(1);
#pragma unroll
        for (int tt = 0; tt < 4; ++tt) {
            const int row = tt * 16 + l16;
            f32x4 c2 = {0.f, 0.f, 0.f, 0.f};
#pragma unroll
            for (int ks = 0; ks < 4; ++ks)
                c2 = mfma16(aq[ks], ld8(kv + row * 128 + (((ks * 4 + quad) ^ swz) << 3)), c2);
            S[kt * 4 + tt] = c2;
        }
        __builtin_amdgcn_s_setprio(0);
        __syncthreads();
    }

    const float scale = 0.08838834764831845f;  // 1/sqrt(128)
    float mx[4] = {-3.0e38f, -3.0e38f, -3.0e38f, -3.0e38f};
#pragma unroll
    for (int t = 0; t < 32; ++t)
#pragma unroll
        for (int g = 0; g < 4; ++g) mx[g] = fmaxf(mx[g], S[t][g]);
#pragma unroll
    for (int off = 1; off < 16; off <<= 1)
#pragma unroll
        for (int g = 0; g < 4; ++g) mx[g] = fmaxf(mx[g], __shfl_xor(mx[g], off));

    float sm[4] = {0.f, 0.f, 0.f, 0.f};
    const float* mrow = kmask + (size_t)b * Lk;
#pragma unroll
    for (int t = 0; t < 32; ++t) {
        const float mv = mrow[t * 16 + l16];
#pragma unroll
        for (int g = 0; g < 4; ++g) {
            float p = (mv != 0.f) ? __expf((S[t][g] - mx[g]) * scale) : 0.f;
            S[t][g] = p;
            sm[g] += p;
        }
    }
#pragma unroll
    for (int off = 1; off < 16; off <<= 1)
#pragma unroll
        for (int g = 0; g < 4; ++g) sm[g] += __shfl_xor(sm[g], off);
    float rs[4];
#pragma unroll
    for (int g = 0; g < 4; ++g) rs[g] = 1.f / sm[g];

    // P: C-layout regs -> LDS [row16][520] in region A
    bf16* pw = smem + wave * 8320;
#pragma unroll
    for (int t = 0; t < 32; ++t) {
        const int col = t * 16 + l16;
#pragma unroll
        for (int g = 0; g < 4; ++g)
            pw[(quad * 4 + g) * 520 + col] = __float2bfloat16(S[t][g] * rs[g]);
    }
    asm volatile("" ::: "memory");
    __syncthreads();

    bf16x8 pa[16];
#pragma unroll
    for (int ks = 0; ks < 16; ++ks)
        pa[ks] = ld8(pw + l16 * 520 + ks * 32 + quad * 8);

    // ---- PV: 8 rounds of V^T tile [16 d-rows][512 m] staged in region B ---
    const bf16* Vb = VT + (size_t)bh * 128 * Lk;
    const size_t orow = (size_t)b * Lq + n0 + wave * 16 + quad * 4;
    for (int dt = 0; dt < 8; ++dt) {
#pragma unroll
        for (int c = 0; c < 8; ++c) {
            const int e = c * 1024 + tid * 8;
            const int r = e >> 9;
            const int j = (e >> 3) & 63;
            gl_lds16(Vb + (size_t)(dt * 16 + r) * Lk + ((j ^ (r & 7)) << 3), kv + e);
        }
        __syncthreads();
        __builtin_amdgcn_s_setprio(1);
        f32x4 c2 = {0.f, 0.f, 0.f, 0.f};
#pragma unroll
        for (int ks = 0; ks < 16; ++ks)
            c2 = mfma16(pa[ks], ld8(kv + l16 * 512 + (((ks * 4 + quad) ^ swz) << 3)), c2);
        __builtin_amdgcn_s_setprio(0);
        const int col = outColOff + h * 128 + dt * 16 + l16;
#pragma unroll
        for (int g = 0; g < 4; ++g)
            Out[(orow + g) * outStride + col] = __float2bfloat16(c2[g]);
        __syncthreads();
    }
}

// ---------------------------------------------------------------------------
extern "C" void kernel_launch(void* const* d_in, const int* in_sizes, int n_in,
                              void* d_out, int out_size, void* d_ws, size_t ws_size,
                              hipStream_t stream)
{
    (void)in_sizes; (void)n_in; (void)out_size; (void)ws_size;
    const float* v   = (const float*)d_in[0];
    const float* q   = (const float*)d_in[1];
    const float* vm  = (const float*)d_in[2];
    const float* qm  = (const float*)d_in[3];
    const float* Wv  = (const float*)d_in[4];
    const float* bv  = (const float*)d_in[5];
    const float* Wq  = (const float*)d_in[6];
    const float* bq  = (const float*)d_in[7];
    const float* Wvo = (const float*)d_in[8];
    const float* bvo = (const float*)d_in[9];
    const float* Wqo = (const float*)d_in[10];
    const float* bqo = (const float*)d_in[11];

    float* out_v = (float*)d_out;
    float* out_q = out_v + (size_t)8192 * 2048;

    bf16* ws = (bf16*)d_ws;
    bf16* v_trans = ws; ws += (size_t)8192 * 6144;
    bf16* q_trans = ws; ws += (size_t)8192 * 6144;
    bf16* vcat    = ws; ws += (size_t)8192 * 4096;   // [v(bf16) | v_update]
    bf16* qcat    = ws; ws += (size_t)8192 * 3072;   // [q(bf16) | q_update]
    bf16* WvT     = ws; ws += (size_t)6144 * 2048;
    bf16* WqT     = ws; ws += (size_t)6144 * 1024;
    bf16* WvoT    = ws; ws += (size_t)2048 * 4096;
    bf16* WqoT    = ws; ws += (size_t)2048 * 3072;
    bf16* VvalT   = ws; ws += (size_t)256 * 128 * 512;
    bf16* QvalT   = ws; ws += (size_t)256 * 128 * 512;
    // 432 MiB of d_ws

    // 1) convert inputs to bf16 into concat-left (also the GEMM A operands)
    cvt_cols_k<<<8192, 256, 0, stream>>>(v, vcat, 8, 4096, 8192 * 256);
    cvt_cols_k<<<4096, 256, 0, stream>>>(q, qcat, 7, 3072, 8192 * 128);

    // 2) weight convert+transpose (f32 R x C -> bf16 C x R)
    cvt_transpose_k<<<dim3(96, 32), 256, 0, stream>>>(Wv,  (unsigned short*)WvT,  6144, 2048);
    cvt_transpose_k<<<dim3(96, 16), 256, 0, stream>>>(Wq,  (unsigned short*)WqT,  6144, 1024);
    cvt_transpose_k<<<dim3(32, 64), 256, 0, stream>>>(Wvo, (unsigned short*)WvoT, 2048, 4096);
    cvt_transpose_k<<<dim3(32, 48), 256, 0, stream>>>(Wqo, (unsigned short*)WqoT, 2048, 3072);

    // 3) input projections (256x256 tiles, 8-phase)
    gemm_bt<bf16><<<dim3(24, 32), 512, 0, stream>>>(vcat, WvT, bv, vm, v_trans, 2048, 4096, 2048, 6144);
    gemm_bt<bf16><<<dim3(24, 32), 512, 0, stream>>>(qcat, WqT, bq, qm, q_trans, 1024, 3072, 1024, 6144);

    // 4) value-slice transposes: [b,n,h,d] -> [bh][d][n]
    transpose_k<<<dim3(2, 8, 256), 256, 0, stream>>>((const unsigned short*)(v_trans + 4096), (unsigned short*)VvalT,
                                                     6144, 512, (size_t)512 * 6144, 128, 65536);
    transpose_k<<<dim3(2, 8, 256), 256, 0, stream>>>((const unsigned short*)(q_trans + 4096), (unsigned short*)QvalT,
                                                     6144, 512, (size_t)512 * 6144, 128, 65536);

    // 5) cross attention
    attn_k<<<dim3(16, 256), 128, 0, stream>>>(v_trans + 2048, q_trans, QvalT, qm, vcat,
                                              512, 512, 6144, 6144, 4096, 2048);
    attn_k<<<dim3(16, 256), 128, 0, stream>>>(q_trans + 2048, v_trans, VvalT, vm, qcat,
                                              512, 512, 6144, 6144, 3072, 1024);

    // 6) output projections -> d_out (f32, LDS-staged stores)
    gemm_bt<float><<<dim3(8, 32), 512, 0, stream>>>(vcat, WvoT, bvo, nullptr, out_v, 4096, 4096, 4096, 2048);
    gemm_bt<float><<<dim3(8, 32), 512, 0, stream>>>(qcat, WqoT, bqo, nullptr, out_q, 3072, 3072, 3072, 2048);
}